// Round 5
// baseline (5590.860 us; speedup 1.0000x reference)
//
#include <hip/hip_runtime.h>

#define Bz 32
#define Tz 256
#define Ez 256
#define Hz 256
#define Kz 48
#define G4 1024   // 4*H
#define H2 512    // 2*H

typedef __attribute__((ext_vector_type(8))) short short8;
typedef __attribute__((ext_vector_type(4))) float f32x4;
typedef unsigned short ushort_t;
typedef unsigned int uint_t;
typedef unsigned long long ull_t;

__device__ __forceinline__ float bf2f(ushort_t u) {
    unsigned int x = ((unsigned int)u) << 16;
    union { unsigned int i; float f; } c; c.i = x; return c.f;
}
__device__ __forceinline__ ushort_t f2bf(float f) {
    union { float f; unsigned int i; } c; c.f = f;
    unsigned int x = c.i;
    unsigned int lsb = (x >> 16) & 1u;
    x += 0x7fffu + lsb;
    return (ushort_t)(x >> 16);
}
__device__ __forceinline__ float sigm(float x) { return 1.f / (1.f + __expf(-x)); }
__device__ __forceinline__ float tanh_f(float x) { return 1.f - 2.f / (__expf(2.f * x) + 1.f); }

#define MFMA16(a, b, c) __builtin_amdgcn_mfma_f32_16x16x32_bf16((a), (b), (c), 0, 0, 0)

// ---------------- fp32 -> bf16 weight conversion, all 9 matrices in one dispatch ----------------
struct CvtArgs {
    const float* s[9];
    ushort_t* d[9];
    int n[9];
};
__global__ __launch_bounds__(256) void cvt_all(CvtArgs a)
{
    int y = blockIdx.y;
    const float* src = a.s[y];
    ushort_t* dst = a.d[y];
    int n = a.n[y];
    int i = (blockIdx.x * 256 + threadIdx.x) * 4;
    if (i < n) {
        float4 v = *(const float4*)(src + i);
        ushort_t o[4] = { f2bf(v.x), f2bf(v.y), f2bf(v.z), f2bf(v.w) };
        *(uint2*)(dst + i) = *(uint2*)o;
    }
}

// ---------------- embedding gather (fp32 -> bf16) + mask output ----------------
__global__ __launch_bounds__(64) void embed_kernel(
    const int* __restrict__ sent, const float* __restrict__ embed,
    ushort_t* __restrict__ emb, float* __restrict__ mask_out)
{
    int blk = blockIdx.x;             // b*T + t
    int b = blk >> 8, t = blk & 255;
    int s = sent[blk];
    int tid = threadIdx.x;            // 64 threads x 4 elems
    float4 v = *(const float4*)(embed + (size_t)s * Ez + tid * 4);
    ushort_t o[4] = { f2bf(v.x), f2bf(v.y), f2bf(v.z), f2bf(v.w) };
    *(uint2*)(emb + ((size_t)t * Bz + b) * Ez + tid * 4) = *(uint2*)o;
    if (tid == 0) mask_out[blk] = (s != 0) ? 1.0f : 0.0f;
}

// ---------------- input-projection GEMM: C = A @ W^T + bias (both dirs via blockIdx.z) ----------------
__global__ __launch_bounds__(256) void gemm_xproj(
    const ushort_t* __restrict__ A,                                      // (M, Kd) bf16
    const ushort_t* __restrict__ Wf, const ushort_t* __restrict__ Wb,    // (1024, Kd) bf16
    const float* __restrict__ biasf, const float* __restrict__ biasb,    // (1024,) fp32
    ushort_t* __restrict__ Cf, ushort_t* __restrict__ Cb,                // (M, 1024) bf16
    int M, int Kd)
{
    const ushort_t* W = blockIdx.z ? Wb : Wf;
    const float* bias = blockIdx.z ? biasb : biasf;
    ushort_t* C = blockIdx.z ? Cb : Cf;
    int m0 = blockIdx.x * 64, n0 = blockIdx.y * 64;
    int tid = threadIdx.x, l = tid & 63, w = tid >> 6;
    int mw = m0 + (w & 1) * 32, nw = n0 + (w >> 1) * 32;
    int lr = l & 15, lq = l >> 4;
    f32x4 acc[2][2] = {};
    for (int ko = 0; ko < Kd; ko += 32) {
        short8 a0 = *(const short8*)(A + (size_t)(mw + lr) * Kd + ko + lq * 8);
        short8 a1 = *(const short8*)(A + (size_t)(mw + 16 + lr) * Kd + ko + lq * 8);
        short8 b0 = *(const short8*)(W + (size_t)(nw + lr) * Kd + ko + lq * 8);
        short8 b1 = *(const short8*)(W + (size_t)(nw + 16 + lr) * Kd + ko + lq * 8);
        acc[0][0] = MFMA16(a0, b0, acc[0][0]);
        acc[0][1] = MFMA16(a0, b1, acc[0][1]);
        acc[1][0] = MFMA16(a1, b0, acc[1][0]);
        acc[1][1] = MFMA16(a1, b1, acc[1][1]);
    }
    for (int mt = 0; mt < 2; mt++)
        for (int nt = 0; nt < 2; nt++)
            for (int r = 0; r < 4; r++) {
                int row = mw + mt * 16 + lq * 4 + r;
                int col = nw + nt * 16 + lr;
                float v = acc[mt][nt][r] + bias[col];
                C[(size_t)row * G4 + col] = f2bf(v);
            }
}

// ---------------- LSTM recurrence: 64 independent single-wave blocks ----------------
// block = one wave. dir = bid>>5, v = bid&31: owns hidden units [v*8, v*8+8), all 32 batches.
// Gate columns re-interleaved as cI = (u_local)*4 + gate so one wave's 32 MFMA output
// cols = its 8 units x 4 gates -> cell update stays inside the wave. Zero barriers.
// h exchange: tagged 8B words (tag bit14 of elem0, tau(s)=((s>>1)^s)&1) via relaxed
// agent-scope atomics; consumers poll A-fragments directly into registers.
__global__ __launch_bounds__(64, 1) void lstm_layer(
    const ushort_t* __restrict__ Whh_f, const ushort_t* __restrict__ Whh_b,  // (1024,256) bf16
    const ushort_t* __restrict__ Xp_f, const ushort_t* __restrict__ Xp_b,    // (T*B, 1024) preact incl bias
    const int* __restrict__ lengths,                                         // (B,)
    ushort_t* __restrict__ hcat,                                             // (T*B, 512)
    ull_t* __restrict__ hbuf)       // [buf(2)][dir(2)][B][H/4] 8B words, pre-zeroed
{
    __shared__ float sG[Bz][37];      // [b][cI] gates scratch (stride 37 breaks conflicts)
    __shared__ ull_t sHold[Bz][2];    // [b][half]: this wave's 8 units of h (for mask-hold)

    int bid = blockIdx.x;
    int dir = bid >> 5;
    int v   = bid & 31;
    int U0  = v * 8;
    const ushort_t* Whh = dir ? Whh_b : Whh_f;
    const ushort_t* Xp  = dir ? Xp_b  : Xp_f;
    int lane = threadIdx.x;
    int lr = lane & 15, lq = lane >> 4;          // lq in 0..3

    // B fragments resident in registers: tile tau covers cols cI = tau*16 + lr
    // cI -> (u = U0 + (cI>>2), g = cI&3); Whh row = g*Hz + u
    short8 bw0[8], bw1[8];
    int gA, gB;
    {
        int u0 = U0 + (lr >> 2), g = lr & 3;
        gA = g * Hz + u0;            // Xp col for tile 0
        gB = gA + 4;                 // tile 1 (u0+4)
        const ushort_t* W0 = Whh + (size_t)gA * Hz;
        const ushort_t* W1 = Whh + (size_t)gB * Hz;
        #pragma unroll
        for (int k = 0; k < 8; k++) {
            bw0[k] = *(const short8*)(W0 + k * 32 + lq * 8);
            bw1[k] = *(const short8*)(W1 + k * 32 + lq * 8);
        }
    }

    // elementwise mapping: lane -> (batch eb, unit-quad half)
    int eb = lane & 31, half = lane >> 5;
    int lenb = lengths[eb];
    float c4[4] = {0.f, 0.f, 0.f, 0.f};
    int lqold = v & 3, kold = v >> 2;   // which polled words contain this wave's own units

    for (int s = 0; s < Tz; s++) {
        int t_act = dir ? (Tz - 1 - s) : s;
        const ushort_t* Xrow = Xp + (size_t)t_act * Bz * G4;

        // prefetch Xp gate-preacts (independent of h)
        float xv00[4], xv01[4], xv10[4], xv11[4];
        #pragma unroll
        for (int r = 0; r < 4; r++) {
            int b0 = lq * 4 + r, b1 = 16 + lq * 4 + r;
            xv00[r] = bf2f(Xrow[(size_t)b0 * G4 + gA]);
            xv01[r] = bf2f(Xrow[(size_t)b0 * G4 + gB]);
            xv10[r] = bf2f(Xrow[(size_t)b1 * G4 + gA]);
            xv11[r] = bf2f(Xrow[(size_t)b1 * G4 + gB]);
        }

        // ---- poll A-fragments directly: word i = (m=i>>4, k=(i>>1)&7, p=i&1) ----
        const ull_t* hcur = hbuf + ((s & 1) * 2 + dir) * (Bz * Hz / 4);
        const ull_t* h0p = hcur + lr * 64 + lq * 2;     // batch lr
        const ull_t* h1p = h0p + 16 * 64;               // batch 16+lr
        uint_t tagc = (uint_t)(((s >> 1) ^ s) & 1);
        ull_t vals[32];
        uint_t pend = 0xffffffffu;
        while (pend) {
            #pragma unroll
            for (int i = 0; i < 32; i++) {
                if (pend & (1u << i)) {
                    const ull_t* bp = (i < 16) ? h0p : h1p;
                    vals[i] = __hip_atomic_load(bp + ((i >> 1) & 7) * 8 + (i & 1),
                                                __ATOMIC_RELAXED, __HIP_MEMORY_SCOPE_AGENT);
                }
            }
            #pragma unroll
            for (int i = 0; i < 32; i++)
                if ((pend & (1u << i)) && (((uint_t)(vals[i] >> 14) & 1u) == tagc))
                    pend &= ~(1u << i);
        }
        #pragma unroll
        for (int i = 0; i < 32; i++) vals[i] &= ~(1ull << 14);

        // stash this wave's own old-h (units U0..U0+8) for the mask-hold path
        if (lq == lqold) {
            sHold[lr][0]      = vals[kold * 2];
            sHold[lr][1]      = vals[kold * 2 + 1];
            sHold[16 + lr][0] = vals[16 + kold * 2];
            sHold[16 + lr][1] = vals[16 + kold * 2 + 1];
        }

        // ---- 32 MFMAs: gates for 32 batches x 32 interleaved cols ----
        f32x4 acc00 = {}, acc01 = {}, acc10 = {}, acc11 = {};
        #pragma unroll
        for (int k = 0; k < 8; k++) {
            union { ull_t u[2]; short8 s8; } a0, a1;
            a0.u[0] = vals[k * 2];      a0.u[1] = vals[k * 2 + 1];
            a1.u[0] = vals[16 + k * 2]; a1.u[1] = vals[16 + k * 2 + 1];
            acc00 = MFMA16(a0.s8, bw0[k], acc00);
            acc01 = MFMA16(a0.s8, bw1[k], acc01);
            acc10 = MFMA16(a1.s8, bw0[k], acc10);
            acc11 = MFMA16(a1.s8, bw1[k], acc11);
        }
        // gates + Xp preact -> LDS scratch (C-layout: col=lr, row=lq*4+r)
        #pragma unroll
        for (int r = 0; r < 4; r++) {
            sG[lq * 4 + r][lr]           = acc00[r] + xv00[r];
            sG[lq * 4 + r][16 + lr]      = acc01[r] + xv01[r];
            sG[16 + lq * 4 + r][lr]      = acc10[r] + xv10[r];
            sG[16 + lq * 4 + r][16 + lr] = acc11[r] + xv11[r];
        }
        __syncthreads();   // single-wave: cheap ordering point for sG/sHold

        // ---- cell update: lane owns (batch eb, units U0+half*4 .. +4) ----
        int msk = (t_act < lenb);
        ull_t hold8 = sHold[eb][half];
        const ushort_t* ho = (const ushort_t*)&hold8;
        ushort_t hx[4], hc[4];
        #pragma unroll
        for (int j = 0; j < 4; j++) {
            int cb = half * 16 + j * 4;
            float gi = sG[eb][cb], gf = sG[eb][cb + 1], gg = sG[eb][cb + 2], go = sG[eb][cb + 3];
            float c2 = sigm(gf) * c4[j] + sigm(gi) * tanh_f(gg);
            float h2 = sigm(go) * tanh_f(c2);
            if (msk) c4[j] = c2;
            ushort_t hn = f2bf(h2);
            hx[j] = msk ? hn : ho[j];
            hc[j] = msk ? hn : (ushort_t)0;
        }
        uint_t tagp = (uint_t)((((s + 1) >> 1) ^ (s + 1)) & 1);
        ull_t wd; __builtin_memcpy(&wd, hx, 8);
        wd |= ((ull_t)tagp) << 14;
        ull_t* hnxt = hbuf + (((s + 1) & 1) * 2 + dir) * (Bz * Hz / 4);
        __hip_atomic_store(&hnxt[eb * 64 + v * 2 + half], wd,
                           __ATOMIC_RELAXED, __HIP_MEMORY_SCOPE_AGENT);
        ull_t wc; __builtin_memcpy(&wc, hc, 8);
        *(ull_t*)(hcat + ((size_t)t_act * Bz + eb) * H2 + dir * Hz + U0 + half * 4) = wc;
    }
}

// ---------------- emit GEMM: (8192,512) @ Wout(48,512)^T + bout -> fp32 out[b][t][k] ----------------
__global__ __launch_bounds__(256) void gemm_emit(
    const ushort_t* __restrict__ A, const ushort_t* __restrict__ Wout,
    const float* __restrict__ bout, float* __restrict__ emit_out)
{
    int tid = threadIdx.x, l = tid & 63, w = tid >> 6;
    int m0 = blockIdx.x * 64 + w * 16;
    int lr = l & 15, lq = l >> 4;
    f32x4 acc[3] = {};
    for (int ko = 0; ko < H2; ko += 32) {
        short8 a = *(const short8*)(A + (size_t)(m0 + lr) * H2 + ko + lq * 8);
        #pragma unroll
        for (int nt = 0; nt < 3; nt++) {
            short8 bfr = *(const short8*)(Wout + (size_t)(nt * 16 + lr) * H2 + ko + lq * 8);
            acc[nt] = MFMA16(a, bfr, acc[nt]);
        }
    }
    #pragma unroll
    for (int nt = 0; nt < 3; nt++)
        #pragma unroll
        for (int r = 0; r < 4; r++) {
            int row = m0 + lq * 4 + r;            // t*B + b
            int col = nt * 16 + lr;
            float v = acc[nt][r] + bout[col];
            int t = row >> 5, b = row & 31;
            emit_out[((size_t)b * Tz + t) * Kz + col] = v;
        }
}

// ---------------- CRF numerator (reads emit from out, [b][t][k] fp32) ----------------
__global__ __launch_bounds__(256) void crf_num(
    const float* __restrict__ emit, const int* __restrict__ sent,
    const int* __restrict__ tags, const int* __restrict__ lengths,
    const float* __restrict__ trans, const float* __restrict__ start_t,
    const float* __restrict__ end_t, float* __restrict__ num)
{
    __shared__ float red[4];
    int b = blockIdx.x, t = threadIdx.x;
    int tg = tags[b * Tz + t];
    float term;
    if (t == 0) {
        term = start_t[tg] + emit[(size_t)b * Tz * Kz + tg];
        int len = lengths[b];
        term += end_t[tags[b * Tz + len - 1]];
    } else if (sent[b * Tz + t] != 0) {
        int tp = tags[b * Tz + t - 1];
        term = trans[tp * Kz + tg] + emit[((size_t)b * Tz + t) * Kz + tg];
    } else term = 0.f;
    #pragma unroll
    for (int off = 1; off < 64; off <<= 1) term += __shfl_xor(term, off);
    int w = t >> 6;
    if ((t & 63) == 0) red[w] = term;
    __syncthreads();
    if (t == 0) num[b] = red[0] + red[1] + red[2] + red[3];
}

// ---------------- CRF denominator (forward algorithm), one wave per batch ----------------
__global__ __launch_bounds__(64) void crf_den(
    const float* __restrict__ emit, const int* __restrict__ lengths,
    const float* __restrict__ trans, const float* __restrict__ start_t,
    const float* __restrict__ end_t, float* __restrict__ den)
{
    __shared__ float sT[Kz * Kz];     // [i*48 + l]
    __shared__ float sS[Kz];
    int b = blockIdx.x, l = threadIdx.x;
    for (int i = l; i < Kz * Kz; i += 64) sT[i] = trans[i];
    int len = lengths[b];
    bool act = l < Kz;
    float s = act ? (start_t[l] + emit[(size_t)b * Tz * Kz + l]) : -1e30f;
    for (int t = 1; t < len; t++) {
        float em = act ? emit[((size_t)b * Tz + t) * Kz + l] : 0.f;
        if (act) sS[l] = s;
        float M = s;
        #pragma unroll
        for (int off = 1; off < 64; off <<= 1) M = fmaxf(M, __shfl_xor(M, off));
        float a0 = 0.f, a1 = 0.f, a2 = 0.f, a3 = 0.f;
        #pragma unroll 4
        for (int i = 0; i < Kz; i += 4) {
            a0 += __expf(sS[i]     + sT[i * Kz + l]       - M);
            a1 += __expf(sS[i + 1] + sT[(i + 1) * Kz + l] - M);
            a2 += __expf(sS[i + 2] + sT[(i + 2) * Kz + l] - M);
            a3 += __expf(sS[i + 3] + sT[(i + 3) * Kz + l] - M);
        }
        float sum = (a0 + a1) + (a2 + a3);
        if (act) s = em + M + __logf(sum);
    }
    float v = act ? (s + end_t[l]) : -1e30f;
    float M = v;
    #pragma unroll
    for (int off = 1; off < 64; off <<= 1) M = fmaxf(M, __shfl_xor(M, off));
    float accv = act ? __expf(v - M) : 0.f;
    #pragma unroll
    for (int off = 1; off < 64; off <<= 1) accv += __shfl_xor(accv, off);
    if (l == 0) den[b] = M + __logf(accv);
}

// ---------------- final loss ----------------
__global__ __launch_bounds__(64) void crf_loss(
    const float* __restrict__ num, const float* __restrict__ den, float* __restrict__ out)
{
    int l = threadIdx.x;
    float v = (l < Bz) ? (num[l] - den[l]) : 0.f;
    #pragma unroll
    for (int off = 1; off < 64; off <<= 1) v += __shfl_xor(v, off);
    if (l == 0) out[0] = v / (float)Bz;
}

extern "C" void kernel_launch(void* const* d_in, const int* in_sizes, int n_in,
                              void* d_out, int out_size, void* d_ws, size_t ws_size,
                              hipStream_t stream) {
    const int* sent      = (const int*)d_in[0];
    const int* lengths   = (const int*)d_in[1];
    const int* tags      = (const int*)d_in[2];
    const float* embed   = (const float*)d_in[3];
    const float* Wih0f = (const float*)d_in[4];
    const float* Whh0f = (const float*)d_in[5];
    const float* b0f   = (const float*)d_in[6];
    const float* Wih0b = (const float*)d_in[7];
    const float* Whh0b = (const float*)d_in[8];
    const float* b0b   = (const float*)d_in[9];
    const float* Wih1f = (const float*)d_in[10];
    const float* Whh1f = (const float*)d_in[11];
    const float* b1f   = (const float*)d_in[12];
    const float* Wih1b = (const float*)d_in[13];
    const float* Whh1b = (const float*)d_in[14];
    const float* b1b   = (const float*)d_in[15];
    const float* Wout  = (const float*)d_in[16];
    const float* bout  = (const float*)d_in[17];
    const float* start_t = (const float*)d_in[18];
    const float* end_t   = (const float*)d_in[19];
    const float* trans   = (const float*)d_in[20];

    char* ws = (char*)d_ws;
    ushort_t* Xp_f  = (ushort_t*)(ws);                        // 16 MB
    ushort_t* Xp_b  = (ushort_t*)(ws + 16777216);             // 16 MB
    ushort_t* hcat  = (ushort_t*)(ws + 33554432);             // 8 MB (layer0 out, then layer1 out)
    ushort_t* emb   = (ushort_t*)(ws + 41943040);             // 4 MB
    ushort_t* Whh0f_c = (ushort_t*)(ws + 46137344);           // 512 KB each
    ushort_t* Whh0b_c = (ushort_t*)(ws + 46661632);
    ushort_t* Wih0f_c = (ushort_t*)(ws + 47185920);
    ushort_t* Wih0b_c = (ushort_t*)(ws + 47710208);
    ushort_t* Wih1f_c = (ushort_t*)(ws + 48234496);           // 1 MB each
    ushort_t* Wih1b_c = (ushort_t*)(ws + 49283072);
    ushort_t* Whh1f_c = (ushort_t*)(ws + 50331648);           // 512 KB each
    ushort_t* Whh1b_c = (ushort_t*)(ws + 50855936);
    ushort_t* Wout_c  = (ushort_t*)(ws + 51380224);           // 48 KB
    ull_t*    hbufL0 = (ull_t*)(ws + 51429376);               // 128 KB: [2][2][B][H/4] 8B words
    ull_t*    hbufL1 = (ull_t*)(ws + 51560448);               // 128 KB
    float*    num   = (float*)   (ws + 51691520);
    float*    den   = (float*)   (ws + 51691776);

    float* out      = (float*)d_out;                          // emit [B][T][K]
    float* loss_out = out + (size_t)Bz * Tz * Kz;             // 393216
    float* mask_out = loss_out + 1;                           // (B,T)

    // zero both layers' h double-buffers (tag protocol: zero word = valid h=0 for step 0)
    hipMemsetAsync(hbufL0, 0, 262144, stream);

    CvtArgs ca;
    ca.s[0] = Whh0f; ca.d[0] = Whh0f_c; ca.n[0] = 262144;
    ca.s[1] = Whh0b; ca.d[1] = Whh0b_c; ca.n[1] = 262144;
    ca.s[2] = Wih0f; ca.d[2] = Wih0f_c; ca.n[2] = 262144;
    ca.s[3] = Wih0b; ca.d[3] = Wih0b_c; ca.n[3] = 262144;
    ca.s[4] = Wih1f; ca.d[4] = Wih1f_c; ca.n[4] = 524288;
    ca.s[5] = Wih1b; ca.d[5] = Wih1b_c; ca.n[5] = 524288;
    ca.s[6] = Whh1f; ca.d[6] = Whh1f_c; ca.n[6] = 262144;
    ca.s[7] = Whh1b; ca.d[7] = Whh1b_c; ca.n[7] = 262144;
    ca.s[8] = Wout;  ca.d[8] = Wout_c;  ca.n[8] = 24576;
    cvt_all<<<dim3(512, 9), 256, 0, stream>>>(ca);

    embed_kernel<<<Bz * Tz, 64, 0, stream>>>(sent, embed, emb, mask_out);

    gemm_xproj<<<dim3(Tz * Bz / 64, G4 / 64, 2), 256, 0, stream>>>(
        emb, Wih0f_c, Wih0b_c, b0f, b0b, Xp_f, Xp_b, Tz * Bz, Ez);

    lstm_layer<<<64, 64, 0, stream>>>(Whh0f_c, Whh0b_c, Xp_f, Xp_b, lengths, hcat, hbufL0);

    gemm_xproj<<<dim3(Tz * Bz / 64, G4 / 64, 2), 256, 0, stream>>>(
        hcat, Wih1f_c, Wih1b_c, b1f, b1b, Xp_f, Xp_b, Tz * Bz, H2);

    lstm_layer<<<64, 64, 0, stream>>>(Whh1f_c, Whh1b_c, Xp_f, Xp_b, lengths, hcat, hbufL1);

    gemm_emit<<<Tz * Bz / 64, 256, 0, stream>>>(hcat, Wout_c, bout, out);

    crf_num<<<Bz, 256, 0, stream>>>(out, sent, tags, lengths, trans, start_t, end_t, num);
    crf_den<<<Bz, 64, 0, stream>>>(out, lengths, trans, start_t, end_t, den);
    crf_loss<<<1, 64, 0, stream>>>(num, den, loss_out);
}

// Round 6
// 3064.797 us; speedup vs baseline: 1.8242x; 1.8242x over previous
//
#include <hip/hip_runtime.h>

#define Bz 32
#define Tz 256
#define Ez 256
#define Hz 256
#define Kz 48
#define G4 1024   // 4*H
#define H2 512    // 2*H

typedef __attribute__((ext_vector_type(8))) short short8;
typedef __attribute__((ext_vector_type(4))) float f32x4;
typedef unsigned short ushort_t;
typedef unsigned int uint_t;
typedef unsigned long long ull_t;

__device__ __forceinline__ float bf2f(ushort_t u) {
    unsigned int x = ((unsigned int)u) << 16;
    union { unsigned int i; float f; } c; c.i = x; return c.f;
}
__device__ __forceinline__ ushort_t f2bf(float f) {
    union { float f; unsigned int i; } c; c.f = f;
    unsigned int x = c.i;
    unsigned int lsb = (x >> 16) & 1u;
    x += 0x7fffu + lsb;
    return (ushort_t)(x >> 16);
}
__device__ __forceinline__ float sigm(float x) { return 1.f / (1.f + __expf(-x)); }
__device__ __forceinline__ float tanh_f(float x) { return 1.f - 2.f / (__expf(2.f * x) + 1.f); }

#define MFMA16(a, b, c) __builtin_amdgcn_mfma_f32_16x16x32_bf16((a), (b), (c), 0, 0, 0)

// ---------------- fp32 -> bf16 weight conversion, all 9 matrices in one dispatch ----------------
struct CvtArgs {
    const float* s[9];
    ushort_t* d[9];
    int n[9];
};
__global__ __launch_bounds__(256) void cvt_all(CvtArgs a)
{
    int y = blockIdx.y;
    const float* src = a.s[y];
    ushort_t* dst = a.d[y];
    int n = a.n[y];
    int i = (blockIdx.x * 256 + threadIdx.x) * 4;
    if (i < n) {
        float4 v = *(const float4*)(src + i);
        ushort_t o[4] = { f2bf(v.x), f2bf(v.y), f2bf(v.z), f2bf(v.w) };
        *(uint2*)(dst + i) = *(uint2*)o;
    }
}

// ---------------- embedding gather (fp32 -> bf16) + mask output ----------------
__global__ __launch_bounds__(64) void embed_kernel(
    const int* __restrict__ sent, const float* __restrict__ embed,
    ushort_t* __restrict__ emb, float* __restrict__ mask_out)
{
    int blk = blockIdx.x;             // b*T + t
    int b = blk >> 8, t = blk & 255;
    int s = sent[blk];
    int tid = threadIdx.x;            // 64 threads x 4 elems
    float4 v = *(const float4*)(embed + (size_t)s * Ez + tid * 4);
    ushort_t o[4] = { f2bf(v.x), f2bf(v.y), f2bf(v.z), f2bf(v.w) };
    *(uint2*)(emb + ((size_t)t * Bz + b) * Ez + tid * 4) = *(uint2*)o;
    if (tid == 0) mask_out[blk] = (s != 0) ? 1.0f : 0.0f;
}

// ---------------- input-projection GEMM: C = A @ W^T + bias (both dirs via blockIdx.z) ----------------
__global__ __launch_bounds__(256) void gemm_xproj(
    const ushort_t* __restrict__ A,                                      // (M, Kd) bf16
    const ushort_t* __restrict__ Wf, const ushort_t* __restrict__ Wb,    // (1024, Kd) bf16
    const float* __restrict__ biasf, const float* __restrict__ biasb,    // (1024,) fp32
    ushort_t* __restrict__ Cf, ushort_t* __restrict__ Cb,                // (M, 1024) bf16
    int M, int Kd)
{
    const ushort_t* W = blockIdx.z ? Wb : Wf;
    const float* bias = blockIdx.z ? biasb : biasf;
    ushort_t* C = blockIdx.z ? Cb : Cf;
    int m0 = blockIdx.x * 64, n0 = blockIdx.y * 64;
    int tid = threadIdx.x, l = tid & 63, w = tid >> 6;
    int mw = m0 + (w & 1) * 32, nw = n0 + (w >> 1) * 32;
    int lr = l & 15, lq = l >> 4;
    f32x4 acc[2][2] = {};
    for (int ko = 0; ko < Kd; ko += 32) {
        short8 a0 = *(const short8*)(A + (size_t)(mw + lr) * Kd + ko + lq * 8);
        short8 a1 = *(const short8*)(A + (size_t)(mw + 16 + lr) * Kd + ko + lq * 8);
        short8 b0 = *(const short8*)(W + (size_t)(nw + lr) * Kd + ko + lq * 8);
        short8 b1 = *(const short8*)(W + (size_t)(nw + 16 + lr) * Kd + ko + lq * 8);
        acc[0][0] = MFMA16(a0, b0, acc[0][0]);
        acc[0][1] = MFMA16(a0, b1, acc[0][1]);
        acc[1][0] = MFMA16(a1, b0, acc[1][0]);
        acc[1][1] = MFMA16(a1, b1, acc[1][1]);
    }
    for (int mt = 0; mt < 2; mt++)
        for (int nt = 0; nt < 2; nt++)
            for (int r = 0; r < 4; r++) {
                int row = mw + mt * 16 + lq * 4 + r;
                int col = nw + nt * 16 + lr;
                float v = acc[mt][nt][r] + bias[col];
                C[(size_t)row * G4 + col] = f2bf(v);
            }
}

// ---------------- LSTM recurrence, one layer, both dirs ----------------
// grid = 32 blocks x 256 threads (4 waves). dir = bid>>4, sub = bid&15
// (block owns hidden units [sub*16, sub*16+16)).
// Wave w: batch tile mw=(w&1)*16, unit pair P=w>>1 (units h0+P*8 .. +8).
// Gate cols interleaved cI = u_loc*4 + gate (done at B-fragment gather) so a
// wave's 32 MFMA cols = complete gate quads for its 8 units -> wave-local update.
// Each lane polls its 16 A-frag words (tag bit14, tau(s)=((s>>1)^s)&1) straight
// into registers via relaxed agent atomics. Zero block barriers in the loop;
// one wave-local lgkmcnt(0) orders the 2KB/wave LDS gate transpose.
__global__ __launch_bounds__(256, 1) void lstm_layer(
    const ushort_t* __restrict__ Whh_f, const ushort_t* __restrict__ Whh_b,  // (1024,256) bf16
    const ushort_t* __restrict__ Xp_f, const ushort_t* __restrict__ Xp_b,    // (T*B, 1024) preact incl bias
    const int* __restrict__ lengths,                                         // (B,)
    ushort_t* __restrict__ hcat,                                             // (T*B, 512)
    ull_t* __restrict__ hbuf)       // [buf(2)][dir(2)][B][H/4] 8B words, pre-zeroed
{
    __shared__ float sG[4][16][34];   // per-wave gates scratch (stride 34: <=2-way)

    int bid = blockIdx.x;
    int dir = bid >> 4;
    int sub = bid & 15;
    int h0 = sub * 16;
    const ushort_t* Whh = dir ? Whh_b : Whh_f;
    const ushort_t* Xp  = dir ? Xp_b  : Xp_f;
    int tid = threadIdx.x, l = tid & 63, w = tid >> 6;
    int lr = l & 15, lq = l >> 4;
    int mw = (w & 1) * 16;       // batch tile
    int P  = w >> 1;             // unit pair
    int U0w = h0 + P * 8;

    // B fragments in registers; col cI=lr -> (unit U0w + (lr>>2), gate lr&3), tile1 = +4 units
    short8 bw0[8], bw1[8];
    int gA = (lr & 3) * Hz + U0w + (lr >> 2);   // Whh row == Xp col, tile 0
    int gB = gA + 4;                             // tile 1
    {
        const ushort_t* W0 = Whh + (size_t)gA * Hz;
        const ushort_t* W1 = Whh + (size_t)gB * Hz;
        #pragma unroll
        for (int k = 0; k < 8; k++) {
            bw0[k] = *(const short8*)(W0 + k * 32 + lq * 8);
            bw1[k] = *(const short8*)(W1 + k * 32 + lq * 8);
        }
    }

    // update lanes: l<32: b_loc = l&15, q = (l>>4)&1 -> units U0w + q*4 .. +4
    int upd = (l < 32);
    int bloc = l & 15;
    int q = (l >> 4) & 1;
    int batch = mw + bloc;
    int lenb = lengths[batch];
    float c4[4] = {0.f, 0.f, 0.f, 0.f};
    ull_t prevw = 0;                               // last published word (untagged)
    int pubw = batch * 64 + sub * 4 + P * 2 + q;   // hbuf word index within buffer
    int hcoff = dir * Hz + U0w + q * 4;            // hcat ushort offset within row

    for (int s = 0; s < Tz; s++) {
        int t_act = dir ? (Tz - 1 - s) : s;
        const ushort_t* Xrow = Xp + (size_t)t_act * Bz * G4;

        // Xp prefetch (independent of h; overlaps the poll)
        float xv0[4], xv1[4];
        #pragma unroll
        for (int r = 0; r < 4; r++) {
            int brow = mw + lq * 4 + r;
            xv0[r] = bf2f(Xrow[(size_t)brow * G4 + gA]);
            xv1[r] = bf2f(Xrow[(size_t)brow * G4 + gB]);
        }

        // ---- poll this lane's 16 A-frag words ----
        const ull_t* hcur = hbuf + ((s & 1) * 2 + dir) * (Bz * Hz / 4);
        const ull_t* rowp = hcur + (size_t)(mw + lr) * 64 + lq * 2;
        uint_t tagc = (uint_t)(((s >> 1) ^ s) & 1);
        ull_t vals[16];
        uint_t pend = 0xffffu;
        while (pend) {
            #pragma unroll
            for (int i = 0; i < 16; i++)
                if (pend & (1u << i))
                    vals[i] = __hip_atomic_load(rowp + (i >> 1) * 8 + (i & 1),
                                                __ATOMIC_RELAXED, __HIP_MEMORY_SCOPE_AGENT);
            #pragma unroll
            for (int i = 0; i < 16; i++)
                if ((pend & (1u << i)) && (((uint_t)(vals[i] >> 14) & 1u) == tagc))
                    pend &= ~(1u << i);
        }
        #pragma unroll
        for (int i = 0; i < 16; i++) vals[i] &= ~(1ull << 14);

        // ---- 16 MFMAs ----
        f32x4 acc0 = {}, acc1 = {};
        #pragma unroll
        for (int k = 0; k < 8; k++) {
            union { ull_t u[2]; short8 s8; } a;
            a.u[0] = vals[k * 2]; a.u[1] = vals[k * 2 + 1];
            acc0 = MFMA16(a.s8, bw0[k], acc0);
            acc1 = MFMA16(a.s8, bw1[k], acc1);
        }
        // gates + Xp -> per-wave LDS transpose
        #pragma unroll
        for (int r = 0; r < 4; r++) {
            sG[w][lq * 4 + r][lr]      = acc0[r] + xv0[r];
            sG[w][lq * 4 + r][16 + lr] = acc1[r] + xv1[r];
        }
        asm volatile("s_waitcnt lgkmcnt(0)" ::: "memory");   // wave-local ordering

        // ---- cell update + tagged publish (lanes 0..31 of each wave) ----
        uint_t tagp = (uint_t)((((s + 1) >> 1) ^ (s + 1)) & 1);
        if (upd) {
            int msk = (t_act < lenb);
            ushort_t hx[4], hc[4];
            const ushort_t* ho = (const ushort_t*)&prevw;
            #pragma unroll
            for (int j = 0; j < 4; j++) {
                int cb = q * 16 + j * 4;
                float gi = sG[w][bloc][cb], gf = sG[w][bloc][cb + 1];
                float gg = sG[w][bloc][cb + 2], go = sG[w][bloc][cb + 3];
                float c2 = sigm(gf) * c4[j] + sigm(gi) * tanh_f(gg);
                float h2 = sigm(go) * tanh_f(c2);
                if (msk) c4[j] = c2;
                ushort_t hn = f2bf(h2);
                hx[j] = msk ? hn : ho[j];
                hc[j] = msk ? hn : (ushort_t)0;
            }
            ull_t wd; __builtin_memcpy(&wd, hx, 8);
            prevw = wd;
            wd |= ((ull_t)tagp) << 14;
            ull_t* hnxt = hbuf + (((s + 1) & 1) * 2 + dir) * (Bz * Hz / 4);
            __hip_atomic_store(&hnxt[pubw], wd,
                               __ATOMIC_RELAXED, __HIP_MEMORY_SCOPE_AGENT);
            ull_t wc; __builtin_memcpy(&wc, hc, 8);
            *(ull_t*)(hcat + ((size_t)t_act * Bz + batch) * H2 + hcoff) = wc;
        }
    }
}

// ---------------- emit GEMM: (8192,512) @ Wout(48,512)^T + bout -> fp32 out[b][t][k] ----------------
__global__ __launch_bounds__(256) void gemm_emit(
    const ushort_t* __restrict__ A, const ushort_t* __restrict__ Wout,
    const float* __restrict__ bout, float* __restrict__ emit_out)
{
    int tid = threadIdx.x, l = tid & 63, w = tid >> 6;
    int m0 = blockIdx.x * 64 + w * 16;
    int lr = l & 15, lq = l >> 4;
    f32x4 acc[3] = {};
    for (int ko = 0; ko < H2; ko += 32) {
        short8 a = *(const short8*)(A + (size_t)(m0 + lr) * H2 + ko + lq * 8);
        #pragma unroll
        for (int nt = 0; nt < 3; nt++) {
            short8 bfr = *(const short8*)(Wout + (size_t)(nt * 16 + lr) * H2 + ko + lq * 8);
            acc[nt] = MFMA16(a, bfr, acc[nt]);
        }
    }
    #pragma unroll
    for (int nt = 0; nt < 3; nt++)
        #pragma unroll
        for (int r = 0; r < 4; r++) {
            int row = m0 + lq * 4 + r;            // t*B + b
            int col = nt * 16 + lr;
            float v = acc[nt][r] + bout[col];
            int t = row >> 5, b = row & 31;
            emit_out[((size_t)b * Tz + t) * Kz + col] = v;
        }
}

// ---------------- CRF numerator (reads emit from out, [b][t][k] fp32) ----------------
__global__ __launch_bounds__(256) void crf_num(
    const float* __restrict__ emit, const int* __restrict__ sent,
    const int* __restrict__ tags, const int* __restrict__ lengths,
    const float* __restrict__ trans, const float* __restrict__ start_t,
    const float* __restrict__ end_t, float* __restrict__ num)
{
    __shared__ float red[4];
    int b = blockIdx.x, t = threadIdx.x;
    int tg = tags[b * Tz + t];
    float term;
    if (t == 0) {
        term = start_t[tg] + emit[(size_t)b * Tz * Kz + tg];
        int len = lengths[b];
        term += end_t[tags[b * Tz + len - 1]];
    } else if (sent[b * Tz + t] != 0) {
        int tp = tags[b * Tz + t - 1];
        term = trans[tp * Kz + tg] + emit[((size_t)b * Tz + t) * Kz + tg];
    } else term = 0.f;
    #pragma unroll
    for (int off = 1; off < 64; off <<= 1) term += __shfl_xor(term, off);
    int w = t >> 6;
    if ((t & 63) == 0) red[w] = term;
    __syncthreads();
    if (t == 0) num[b] = red[0] + red[1] + red[2] + red[3];
}

// ---------------- CRF denominator (forward algorithm), one wave per batch ----------------
__global__ __launch_bounds__(64) void crf_den(
    const float* __restrict__ emit, const int* __restrict__ lengths,
    const float* __restrict__ trans, const float* __restrict__ start_t,
    const float* __restrict__ end_t, float* __restrict__ den)
{
    __shared__ float sT[Kz * Kz];     // [i*48 + l]
    __shared__ float sS[Kz];
    int b = blockIdx.x, l = threadIdx.x;
    for (int i = l; i < Kz * Kz; i += 64) sT[i] = trans[i];
    int len = lengths[b];
    bool act = l < Kz;
    float s = act ? (start_t[l] + emit[(size_t)b * Tz * Kz + l]) : -1e30f;
    for (int t = 1; t < len; t++) {
        float em = act ? emit[((size_t)b * Tz + t) * Kz + l] : 0.f;
        if (act) sS[l] = s;
        float M = s;
        #pragma unroll
        for (int off = 1; off < 64; off <<= 1) M = fmaxf(M, __shfl_xor(M, off));
        float a0 = 0.f, a1 = 0.f, a2 = 0.f, a3 = 0.f;
        #pragma unroll 4
        for (int i = 0; i < Kz; i += 4) {
            a0 += __expf(sS[i]     + sT[i * Kz + l]       - M);
            a1 += __expf(sS[i + 1] + sT[(i + 1) * Kz + l] - M);
            a2 += __expf(sS[i + 2] + sT[(i + 2) * Kz + l] - M);
            a3 += __expf(sS[i + 3] + sT[(i + 3) * Kz + l] - M);
        }
        float sum = (a0 + a1) + (a2 + a3);
        if (act) s = em + M + __logf(sum);
    }
    float v = act ? (s + end_t[l]) : -1e30f;
    float M = v;
    #pragma unroll
    for (int off = 1; off < 64; off <<= 1) M = fmaxf(M, __shfl_xor(M, off));
    float accv = act ? __expf(v - M) : 0.f;
    #pragma unroll
    for (int off = 1; off < 64; off <<= 1) accv += __shfl_xor(accv, off);
    if (l == 0) den[b] = M + __logf(accv);
}

// ---------------- final loss ----------------
__global__ __launch_bounds__(64) void crf_loss(
    const float* __restrict__ num, const float* __restrict__ den, float* __restrict__ out)
{
    int l = threadIdx.x;
    float v = (l < Bz) ? (num[l] - den[l]) : 0.f;
    #pragma unroll
    for (int off = 1; off < 64; off <<= 1) v += __shfl_xor(v, off);
    if (l == 0) out[0] = v / (float)Bz;
}

extern "C" void kernel_launch(void* const* d_in, const int* in_sizes, int n_in,
                              void* d_out, int out_size, void* d_ws, size_t ws_size,
                              hipStream_t stream) {
    const int* sent      = (const int*)d_in[0];
    const int* lengths   = (const int*)d_in[1];
    const int* tags      = (const int*)d_in[2];
    const float* embed   = (const float*)d_in[3];
    const float* Wih0f = (const float*)d_in[4];
    const float* Whh0f = (const float*)d_in[5];
    const float* b0f   = (const float*)d_in[6];
    const float* Wih0b = (const float*)d_in[7];
    const float* Whh0b = (const float*)d_in[8];
    const float* b0b   = (const float*)d_in[9];
    const float* Wih1f = (const float*)d_in[10];
    const float* Whh1f = (const float*)d_in[11];
    const float* b1f   = (const float*)d_in[12];
    const float* Wih1b = (const float*)d_in[13];
    const float* Whh1b = (const float*)d_in[14];
    const float* b1b   = (const float*)d_in[15];
    const float* Wout  = (const float*)d_in[16];
    const float* bout  = (const float*)d_in[17];
    const float* start_t = (const float*)d_in[18];
    const float* end_t   = (const float*)d_in[19];
    const float* trans   = (const float*)d_in[20];

    char* ws = (char*)d_ws;
    ushort_t* Xp_f  = (ushort_t*)(ws);                        // 16 MB
    ushort_t* Xp_b  = (ushort_t*)(ws + 16777216);             // 16 MB
    ushort_t* hcat  = (ushort_t*)(ws + 33554432);             // 8 MB (layer0 out, then layer1 out)
    ushort_t* emb   = (ushort_t*)(ws + 41943040);             // 4 MB
    ushort_t* Whh0f_c = (ushort_t*)(ws + 46137344);           // 512 KB each
    ushort_t* Whh0b_c = (ushort_t*)(ws + 46661632);
    ushort_t* Wih0f_c = (ushort_t*)(ws + 47185920);
    ushort_t* Wih0b_c = (ushort_t*)(ws + 47710208);
    ushort_t* Wih1f_c = (ushort_t*)(ws + 48234496);           // 1 MB each
    ushort_t* Wih1b_c = (ushort_t*)(ws + 49283072);
    ushort_t* Whh1f_c = (ushort_t*)(ws + 50331648);           // 512 KB each
    ushort_t* Whh1b_c = (ushort_t*)(ws + 50855936);
    ushort_t* Wout_c  = (ushort_t*)(ws + 51380224);           // 48 KB
    ull_t*    hbufL0 = (ull_t*)(ws + 51429376);               // 128 KB: [2][2][B][H/4] 8B words
    ull_t*    hbufL1 = (ull_t*)(ws + 51560448);               // 128 KB
    float*    num   = (float*)   (ws + 51691520);
    float*    den   = (float*)   (ws + 51691776);

    float* out      = (float*)d_out;                          // emit [B][T][K]
    float* loss_out = out + (size_t)Bz * Tz * Kz;             // 393216
    float* mask_out = loss_out + 1;                           // (B,T)

    // zero both layers' h double-buffers (tag protocol: zero word = valid h=0 for step 0)
    hipMemsetAsync(hbufL0, 0, 262144, stream);

    CvtArgs ca;
    ca.s[0] = Whh0f; ca.d[0] = Whh0f_c; ca.n[0] = 262144;
    ca.s[1] = Whh0b; ca.d[1] = Whh0b_c; ca.n[1] = 262144;
    ca.s[2] = Wih0f; ca.d[2] = Wih0f_c; ca.n[2] = 262144;
    ca.s[3] = Wih0b; ca.d[3] = Wih0b_c; ca.n[3] = 262144;
    ca.s[4] = Wih1f; ca.d[4] = Wih1f_c; ca.n[4] = 524288;
    ca.s[5] = Wih1b; ca.d[5] = Wih1b_c; ca.n[5] = 524288;
    ca.s[6] = Whh1f; ca.d[6] = Whh1f_c; ca.n[6] = 262144;
    ca.s[7] = Whh1b; ca.d[7] = Whh1b_c; ca.n[7] = 262144;
    ca.s[8] = Wout;  ca.d[8] = Wout_c;  ca.n[8] = 24576;
    cvt_all<<<dim3(512, 9), 256, 0, stream>>>(ca);

    embed_kernel<<<Bz * Tz, 64, 0, stream>>>(sent, embed, emb, mask_out);

    gemm_xproj<<<dim3(Tz * Bz / 64, G4 / 64, 2), 256, 0, stream>>>(
        emb, Wih0f_c, Wih0b_c, b0f, b0b, Xp_f, Xp_b, Tz * Bz, Ez);

    lstm_layer<<<32, 256, 0, stream>>>(Whh0f_c, Whh0b_c, Xp_f, Xp_b, lengths, hcat, hbufL0);

    gemm_xproj<<<dim3(Tz * Bz / 64, G4 / 64, 2), 256, 0, stream>>>(
        hcat, Wih1f_c, Wih1b_c, b1f, b1b, Xp_f, Xp_b, Tz * Bz, H2);

    lstm_layer<<<32, 256, 0, stream>>>(Whh1f_c, Whh1b_c, Xp_f, Xp_b, lengths, hcat, hbufL1);

    gemm_emit<<<Tz * Bz / 64, 256, 0, stream>>>(hcat, Wout_c, bout, out);

    crf_num<<<Bz, 256, 0, stream>>>(out, sent, tags, lengths, trans, start_t, end_t, num);
    crf_den<<<Bz, 64, 0, stream>>>(out, lengths, trans, start_t, end_t, den);
    crf_loss<<<1, 64, 0, stream>>>(num, den, loss_out);
}

// Round 7
// 2000.138 us; speedup vs baseline: 2.7952x; 1.5323x over previous
//
#include <hip/hip_runtime.h>

#define Bz 32
#define Tz 256
#define Ez 256
#define Hz 256
#define Kz 48
#define G4 1024   // 4*H
#define H2 512    // 2*H

typedef __attribute__((ext_vector_type(8))) short short8;
typedef __attribute__((ext_vector_type(4))) float f32x4;
typedef unsigned short ushort_t;
typedef unsigned int uint_t;
typedef unsigned long long ull_t;

__device__ __forceinline__ float bf2f(ushort_t u) {
    unsigned int x = ((unsigned int)u) << 16;
    union { unsigned int i; float f; } c; c.i = x; return c.f;
}
__device__ __forceinline__ ushort_t f2bf(float f) {
    union { float f; unsigned int i; } c; c.f = f;
    unsigned int x = c.i;
    unsigned int lsb = (x >> 16) & 1u;
    x += 0x7fffu + lsb;
    return (ushort_t)(x >> 16);
}
__device__ __forceinline__ float sigm(float x) { return 1.f / (1.f + __expf(-x)); }
__device__ __forceinline__ float tanh_f(float x) { return 1.f - 2.f / (__expf(2.f * x) + 1.f); }

#define MFMA16(a, b, c) __builtin_amdgcn_mfma_f32_16x16x32_bf16((a), (b), (c), 0, 0, 0)

// ---------------- fp32 -> bf16 weight conversion, all 9 matrices in one dispatch ----------------
struct CvtArgs {
    const float* s[9];
    ushort_t* d[9];
    int n[9];
};
__global__ __launch_bounds__(256) void cvt_all(CvtArgs a)
{
    int y = blockIdx.y;
    const float* src = a.s[y];
    ushort_t* dst = a.d[y];
    int n = a.n[y];
    int i = (blockIdx.x * 256 + threadIdx.x) * 4;
    if (i < n) {
        float4 v = *(const float4*)(src + i);
        ushort_t o[4] = { f2bf(v.x), f2bf(v.y), f2bf(v.z), f2bf(v.w) };
        *(uint2*)(dst + i) = *(uint2*)o;
    }
}

// ---------------- embedding gather (fp32 -> bf16) + mask output ----------------
__global__ __launch_bounds__(64) void embed_kernel(
    const int* __restrict__ sent, const float* __restrict__ embed,
    ushort_t* __restrict__ emb, float* __restrict__ mask_out)
{
    int blk = blockIdx.x;             // b*T + t
    int b = blk >> 8, t = blk & 255;
    int s = sent[blk];
    int tid = threadIdx.x;            // 64 threads x 4 elems
    float4 v = *(const float4*)(embed + (size_t)s * Ez + tid * 4);
    ushort_t o[4] = { f2bf(v.x), f2bf(v.y), f2bf(v.z), f2bf(v.w) };
    *(uint2*)(emb + ((size_t)t * Bz + b) * Ez + tid * 4) = *(uint2*)o;
    if (tid == 0) mask_out[blk] = (s != 0) ? 1.0f : 0.0f;
}

// ---------------- input-projection GEMM: C = A @ W^T + bias (both dirs via blockIdx.z) ----------------
__global__ __launch_bounds__(256) void gemm_xproj(
    const ushort_t* __restrict__ A,                                      // (M, Kd) bf16
    const ushort_t* __restrict__ Wf, const ushort_t* __restrict__ Wb,    // (1024, Kd) bf16
    const float* __restrict__ biasf, const float* __restrict__ biasb,    // (1024,) fp32
    ushort_t* __restrict__ Cf, ushort_t* __restrict__ Cb,                // (M, 1024) bf16
    int M, int Kd)
{
    const ushort_t* W = blockIdx.z ? Wb : Wf;
    const float* bias = blockIdx.z ? biasb : biasf;
    ushort_t* C = blockIdx.z ? Cb : Cf;
    int m0 = blockIdx.x * 64, n0 = blockIdx.y * 64;
    int tid = threadIdx.x, l = tid & 63, w = tid >> 6;
    int mw = m0 + (w & 1) * 32, nw = n0 + (w >> 1) * 32;
    int lr = l & 15, lq = l >> 4;
    f32x4 acc[2][2] = {};
    for (int ko = 0; ko < Kd; ko += 32) {
        short8 a0 = *(const short8*)(A + (size_t)(mw + lr) * Kd + ko + lq * 8);
        short8 a1 = *(const short8*)(A + (size_t)(mw + 16 + lr) * Kd + ko + lq * 8);
        short8 b0 = *(const short8*)(W + (size_t)(nw + lr) * Kd + ko + lq * 8);
        short8 b1 = *(const short8*)(W + (size_t)(nw + 16 + lr) * Kd + ko + lq * 8);
        acc[0][0] = MFMA16(a0, b0, acc[0][0]);
        acc[0][1] = MFMA16(a0, b1, acc[0][1]);
        acc[1][0] = MFMA16(a1, b0, acc[1][0]);
        acc[1][1] = MFMA16(a1, b1, acc[1][1]);
    }
    for (int mt = 0; mt < 2; mt++)
        for (int nt = 0; nt < 2; nt++)
            for (int r = 0; r < 4; r++) {
                int row = mw + mt * 16 + lq * 4 + r;
                int col = nw + nt * 16 + lr;
                float v = acc[mt][nt][r] + bias[col];
                C[(size_t)row * G4 + col] = f2bf(v);
            }
}

// ---------------- LSTM recurrence, one layer, both dirs ----------------
// grid = 32 blocks x 256 threads (4 waves). dir = bid>>4, sub = bid&15
// (block owns hidden units [sub*16, sub*16+16)).
// Detection engine (R4-proven): cooperative poll, 8 tagged words/thread covering
// the full 16KB h state, straight into registers, then sH + ONE barrier.
// Compute (R6-proven): gate cols interleaved cI=u_loc*4+gate at B-gather so each
// wave's 32 MFMA cols are complete gate quads for its 8 units -> wave-local
// update, no second barrier (safe: a thread's sH overwrite requires full detect,
// which transitively requires every local wave's publish, which implies all
// prior-step sH/sG reads retired). Xp prefetched BEFORE the poll (off critical
// path). Publish (tag bit14, tau(s)=((s>>1)^s)&1) before the hcat store.
#define LDK 264         // 256 + 8 pad (bf16 elems)

__global__ __launch_bounds__(256, 1) void lstm_layer(
    const ushort_t* __restrict__ Whh_f, const ushort_t* __restrict__ Whh_b,  // (1024,256) bf16
    const ushort_t* __restrict__ Xp_f, const ushort_t* __restrict__ Xp_b,    // (T*B, 1024) preact incl bias
    const int* __restrict__ lengths,                                         // (B,)
    ushort_t* __restrict__ hcat,                                             // (T*B, 512)
    ull_t* __restrict__ hbuf)       // [buf(2)][dir(2)][B][H/4] 8B words, pre-zeroed
{
    __shared__ __attribute__((aligned(16))) ushort_t sH[Bz][LDK];
    __shared__ float sG[4][16][34];   // per-wave gates scratch (stride 34: <=2-way)

    int bid = blockIdx.x;
    int dir = bid >> 4;
    int sub = bid & 15;
    int h0 = sub * 16;
    const ushort_t* Whh = dir ? Whh_b : Whh_f;
    const ushort_t* Xp  = dir ? Xp_b  : Xp_f;
    int tid = threadIdx.x, l = tid & 63, w = tid >> 6;
    int lr = l & 15, lq = l >> 4;
    int mw = (w & 1) * 16;       // batch tile
    int P  = w >> 1;             // unit pair
    int U0w = h0 + P * 8;

    // B fragments in registers; col cI=lr -> (unit U0w + (lr>>2), gate lr&3), tile1 = +4 units
    short8 bw0[8], bw1[8];
    int gA = (lr & 3) * Hz + U0w + (lr >> 2);   // Whh row == Xp col, tile 0
    int gB = gA + 4;                             // tile 1
    {
        const ushort_t* W0 = Whh + (size_t)gA * Hz;
        const ushort_t* W1 = Whh + (size_t)gB * Hz;
        #pragma unroll
        for (int k = 0; k < 8; k++) {
            bw0[k] = *(const short8*)(W0 + k * 32 + lq * 8);
            bw1[k] = *(const short8*)(W1 + k * 32 + lq * 8);
        }
    }

    // update lanes: l<32: b_loc = l&15, q = (l>>4)&1 -> units U0w + q*4 .. +4
    int upd = (l < 32);
    int bloc = l & 15;
    int q = (l >> 4) & 1;
    int batch = mw + bloc;
    int lenb = lengths[batch];
    float c4[4] = {0.f, 0.f, 0.f, 0.f};
    ull_t prevw = 0;                               // last published word (untagged)
    int pubw = batch * 64 + sub * 4 + P * 2 + q;   // hbuf word index within buffer
    int hcoff = dir * Hz + U0w + q * 4;            // hcat ushort offset within row

    for (int s = 0; s < Tz; s++) {
        int t_act = dir ? (Tz - 1 - s) : s;
        const ushort_t* Xrow = Xp + (size_t)t_act * Bz * G4;

        // Xp prefetch (independent of h; overlaps the poll)
        float xv0[4], xv1[4];
        #pragma unroll
        for (int r = 0; r < 4; r++) {
            int brow = mw + lq * 4 + r;
            xv0[r] = bf2f(Xrow[(size_t)brow * G4 + gA]);
            xv1[r] = bf2f(Xrow[(size_t)brow * G4 + gB]);
        }

        // ---- cooperative poll: 8 words/thread covers all 2048 words ----
        const ull_t* hcur = hbuf + ((s & 1) * 2 + dir) * (Bz * Hz / 4);
        uint_t tagc = (uint_t)(((s >> 1) ^ s) & 1);
        ull_t vals[8];
        uint_t pend = 0xffu;
        while (pend) {
            #pragma unroll
            for (int k = 0; k < 8; k++)
                if (pend & (1u << k))
                    vals[k] = __hip_atomic_load(&hcur[k * 256 + tid],
                                                __ATOMIC_RELAXED, __HIP_MEMORY_SCOPE_AGENT);
            #pragma unroll
            for (int k = 0; k < 8; k++)
                if ((pend & (1u << k)) && (((uint_t)(vals[k] >> 14) & 1u) == tagc))
                    pend &= ~(1u << k);
        }
        // write sH only AFTER full detect (overwrite-safety invariant)
        #pragma unroll
        for (int k = 0; k < 8; k++) {
            int idx = k * 256 + tid;
            *(ull_t*)(&sH[idx >> 6][(idx & 63) * 4]) = vals[k] & ~(1ull << 14);
        }
        __syncthreads();   // the ONE barrier per step

        // ---- 16 MFMAs (A from sH, B resident) ----
        f32x4 acc0 = {}, acc1 = {};
        #pragma unroll
        for (int k = 0; k < 8; k++) {
            short8 a = *(const short8*)(&sH[mw + lr][k * 32 + lq * 8]);
            acc0 = MFMA16(a, bw0[k], acc0);
            acc1 = MFMA16(a, bw1[k], acc1);
        }
        // gates + Xp -> per-wave LDS transpose
        #pragma unroll
        for (int r = 0; r < 4; r++) {
            sG[w][lq * 4 + r][lr]      = acc0[r] + xv0[r];
            sG[w][lq * 4 + r][16 + lr] = acc1[r] + xv1[r];
        }
        asm volatile("s_waitcnt lgkmcnt(0)" ::: "memory");   // wave-local ordering

        // ---- cell update + tagged publish (lanes 0..31 of each wave) ----
        uint_t tagp = (uint_t)((((s + 1) >> 1) ^ (s + 1)) & 1);
        if (upd) {
            int msk = (t_act < lenb);
            ushort_t hx[4], hc[4];
            const ushort_t* ho = (const ushort_t*)&prevw;
            #pragma unroll
            for (int j = 0; j < 4; j++) {
                int cb = q * 16 + j * 4;
                float gi = sG[w][bloc][cb], gf = sG[w][bloc][cb + 1];
                float gg = sG[w][bloc][cb + 2], go = sG[w][bloc][cb + 3];
                float c2 = sigm(gf) * c4[j] + sigm(gi) * tanh_f(gg);
                float h2 = sigm(go) * tanh_f(c2);
                if (msk) c4[j] = c2;
                ushort_t hn = f2bf(h2);
                hx[j] = msk ? hn : ho[j];
                hc[j] = msk ? hn : (ushort_t)0;
            }
            ull_t wd; __builtin_memcpy(&wd, hx, 8);
            prevw = wd;
            wd |= ((ull_t)tagp) << 14;
            ull_t* hnxt = hbuf + (((s + 1) & 1) * 2 + dir) * (Bz * Hz / 4);
            __hip_atomic_store(&hnxt[pubw], wd,
                               __ATOMIC_RELAXED, __HIP_MEMORY_SCOPE_AGENT);
            ull_t wc; __builtin_memcpy(&wc, hc, 8);
            *(ull_t*)(hcat + ((size_t)t_act * Bz + batch) * H2 + hcoff) = wc;
        }
    }
}

// ---------------- emit GEMM: (8192,512) @ Wout(48,512)^T + bout -> fp32 out[b][t][k] ----------------
__global__ __launch_bounds__(256) void gemm_emit(
    const ushort_t* __restrict__ A, const ushort_t* __restrict__ Wout,
    const float* __restrict__ bout, float* __restrict__ emit_out)
{
    int tid = threadIdx.x, l = tid & 63, w = tid >> 6;
    int m0 = blockIdx.x * 64 + w * 16;
    int lr = l & 15, lq = l >> 4;
    f32x4 acc[3] = {};
    for (int ko = 0; ko < H2; ko += 32) {
        short8 a = *(const short8*)(A + (size_t)(m0 + lr) * H2 + ko + lq * 8);
        #pragma unroll
        for (int nt = 0; nt < 3; nt++) {
            short8 bfr = *(const short8*)(Wout + (size_t)(nt * 16 + lr) * H2 + ko + lq * 8);
            acc[nt] = MFMA16(a, bfr, acc[nt]);
        }
    }
    #pragma unroll
    for (int nt = 0; nt < 3; nt++)
        #pragma unroll
        for (int r = 0; r < 4; r++) {
            int row = m0 + lq * 4 + r;            // t*B + b
            int col = nt * 16 + lr;
            float v = acc[nt][r] + bout[col];
            int t = row >> 5, b = row & 31;
            emit_out[((size_t)b * Tz + t) * Kz + col] = v;
        }
}

// ---------------- CRF numerator (reads emit from out, [b][t][k] fp32) ----------------
__global__ __launch_bounds__(256) void crf_num(
    const float* __restrict__ emit, const int* __restrict__ sent,
    const int* __restrict__ tags, const int* __restrict__ lengths,
    const float* __restrict__ trans, const float* __restrict__ start_t,
    const float* __restrict__ end_t, float* __restrict__ num)
{
    __shared__ float red[4];
    int b = blockIdx.x, t = threadIdx.x;
    int tg = tags[b * Tz + t];
    float term;
    if (t == 0) {
        term = start_t[tg] + emit[(size_t)b * Tz * Kz + tg];
        int len = lengths[b];
        term += end_t[tags[b * Tz + len - 1]];
    } else if (sent[b * Tz + t] != 0) {
        int tp = tags[b * Tz + t - 1];
        term = trans[tp * Kz + tg] + emit[((size_t)b * Tz + t) * Kz + tg];
    } else term = 0.f;
    #pragma unroll
    for (int off = 1; off < 64; off <<= 1) term += __shfl_xor(term, off);
    int w = t >> 6;
    if ((t & 63) == 0) red[w] = term;
    __syncthreads();
    if (t == 0) num[b] = red[0] + red[1] + red[2] + red[3];
}

// ---------------- CRF denominator (forward algorithm), one wave per batch ----------------
__global__ __launch_bounds__(64) void crf_den(
    const float* __restrict__ emit, const int* __restrict__ lengths,
    const float* __restrict__ trans, const float* __restrict__ start_t,
    const float* __restrict__ end_t, float* __restrict__ den)
{
    __shared__ float sT[Kz * Kz];     // [i*48 + l]
    __shared__ float sS[Kz];
    int b = blockIdx.x, l = threadIdx.x;
    for (int i = l; i < Kz * Kz; i += 64) sT[i] = trans[i];
    int len = lengths[b];
    bool act = l < Kz;
    float s = act ? (start_t[l] + emit[(size_t)b * Tz * Kz + l]) : -1e30f;
    for (int t = 1; t < len; t++) {
        float em = act ? emit[((size_t)b * Tz + t) * Kz + l] : 0.f;
        if (act) sS[l] = s;
        float M = s;
        #pragma unroll
        for (int off = 1; off < 64; off <<= 1) M = fmaxf(M, __shfl_xor(M, off));
        float a0 = 0.f, a1 = 0.f, a2 = 0.f, a3 = 0.f;
        #pragma unroll 4
        for (int i = 0; i < Kz; i += 4) {
            a0 += __expf(sS[i]     + sT[i * Kz + l]       - M);
            a1 += __expf(sS[i + 1] + sT[(i + 1) * Kz + l] - M);
            a2 += __expf(sS[i + 2] + sT[(i + 2) * Kz + l] - M);
            a3 += __expf(sS[i + 3] + sT[(i + 3) * Kz + l] - M);
        }
        float sum = (a0 + a1) + (a2 + a3);
        if (act) s = em + M + __logf(sum);
    }
    float v = act ? (s + end_t[l]) : -1e30f;
    float M = v;
    #pragma unroll
    for (int off = 1; off < 64; off <<= 1) M = fmaxf(M, __shfl_xor(M, off));
    float accv = act ? __expf(v - M) : 0.f;
    #pragma unroll
    for (int off = 1; off < 64; off <<= 1) accv += __shfl_xor(accv, off);
    if (l == 0) den[b] = M + __logf(accv);
}

// ---------------- final loss ----------------
__global__ __launch_bounds__(64) void crf_loss(
    const float* __restrict__ num, const float* __restrict__ den, float* __restrict__ out)
{
    int l = threadIdx.x;
    float v = (l < Bz) ? (num[l] - den[l]) : 0.f;
    #pragma unroll
    for (int off = 1; off < 64; off <<= 1) v += __shfl_xor(v, off);
    if (l == 0) out[0] = v / (float)Bz;
}

extern "C" void kernel_launch(void* const* d_in, const int* in_sizes, int n_in,
                              void* d_out, int out_size, void* d_ws, size_t ws_size,
                              hipStream_t stream) {
    const int* sent      = (const int*)d_in[0];
    const int* lengths   = (const int*)d_in[1];
    const int* tags      = (const int*)d_in[2];
    const float* embed   = (const float*)d_in[3];
    const float* Wih0f = (const float*)d_in[4];
    const float* Whh0f = (const float*)d_in[5];
    const float* b0f   = (const float*)d_in[6];
    const float* Wih0b = (const float*)d_in[7];
    const float* Whh0b = (const float*)d_in[8];
    const float* b0b   = (const float*)d_in[9];
    const float* Wih1f = (const float*)d_in[10];
    const float* Whh1f = (const float*)d_in[11];
    const float* b1f   = (const float*)d_in[12];
    const float* Wih1b = (const float*)d_in[13];
    const float* Whh1b = (const float*)d_in[14];
    const float* b1b   = (const float*)d_in[15];
    const float* Wout  = (const float*)d_in[16];
    const float* bout  = (const float*)d_in[17];
    const float* start_t = (const float*)d_in[18];
    const float* end_t   = (const float*)d_in[19];
    const float* trans   = (const float*)d_in[20];

    char* ws = (char*)d_ws;
    ushort_t* Xp_f  = (ushort_t*)(ws);                        // 16 MB
    ushort_t* Xp_b  = (ushort_t*)(ws + 16777216);             // 16 MB
    ushort_t* hcat  = (ushort_t*)(ws + 33554432);             // 8 MB (layer0 out, then layer1 out)
    ushort_t* emb   = (ushort_t*)(ws + 41943040);             // 4 MB
    ushort_t* Whh0f_c = (ushort_t*)(ws + 46137344);           // 512 KB each
    ushort_t* Whh0b_c = (ushort_t*)(ws + 46661632);
    ushort_t* Wih0f_c = (ushort_t*)(ws + 47185920);
    ushort_t* Wih0b_c = (ushort_t*)(ws + 47710208);
    ushort_t* Wih1f_c = (ushort_t*)(ws + 48234496);           // 1 MB each
    ushort_t* Wih1b_c = (ushort_t*)(ws + 49283072);
    ushort_t* Whh1f_c = (ushort_t*)(ws + 50331648);           // 512 KB each
    ushort_t* Whh1b_c = (ushort_t*)(ws + 50855936);
    ushort_t* Wout_c  = (ushort_t*)(ws + 51380224);           // 48 KB
    ull_t*    hbufL0 = (ull_t*)(ws + 51429376);               // 128 KB: [2][2][B][H/4] 8B words
    ull_t*    hbufL1 = (ull_t*)(ws + 51560448);               // 128 KB
    float*    num   = (float*)   (ws + 51691520);
    float*    den   = (float*)   (ws + 51691776);

    float* out      = (float*)d_out;                          // emit [B][T][K]
    float* loss_out = out + (size_t)Bz * Tz * Kz;             // 393216
    float* mask_out = loss_out + 1;                           // (B,T)

    // zero both layers' h double-buffers (tag protocol: zero word = valid h=0 for step 0)
    hipMemsetAsync(hbufL0, 0, 262144, stream);

    CvtArgs ca;
    ca.s[0] = Whh0f; ca.d[0] = Whh0f_c; ca.n[0] = 262144;
    ca.s[1] = Whh0b; ca.d[1] = Whh0b_c; ca.n[1] = 262144;
    ca.s[2] = Wih0f; ca.d[2] = Wih0f_c; ca.n[2] = 262144;
    ca.s[3] = Wih0b; ca.d[3] = Wih0b_c; ca.n[3] = 262144;
    ca.s[4] = Wih1f; ca.d[4] = Wih1f_c; ca.n[4] = 524288;
    ca.s[5] = Wih1b; ca.d[5] = Wih1b_c; ca.n[5] = 524288;
    ca.s[6] = Whh1f; ca.d[6] = Whh1f_c; ca.n[6] = 262144;
    ca.s[7] = Whh1b; ca.d[7] = Whh1b_c; ca.n[7] = 262144;
    ca.s[8] = Wout;  ca.d[8] = Wout_c;  ca.n[8] = 24576;
    cvt_all<<<dim3(512, 9), 256, 0, stream>>>(ca);

    embed_kernel<<<Bz * Tz, 64, 0, stream>>>(sent, embed, emb, mask_out);

    gemm_xproj<<<dim3(Tz * Bz / 64, G4 / 64, 2), 256, 0, stream>>>(
        emb, Wih0f_c, Wih0b_c, b0f, b0b, Xp_f, Xp_b, Tz * Bz, Ez);

    lstm_layer<<<32, 256, 0, stream>>>(Whh0f_c, Whh0b_c, Xp_f, Xp_b, lengths, hcat, hbufL0);

    gemm_xproj<<<dim3(Tz * Bz / 64, G4 / 64, 2), 256, 0, stream>>>(
        hcat, Wih1f_c, Wih1b_c, b1f, b1b, Xp_f, Xp_b, Tz * Bz, H2);

    lstm_layer<<<32, 256, 0, stream>>>(Whh1f_c, Whh1b_c, Xp_f, Xp_b, lengths, hcat, hbufL1);

    gemm_emit<<<Tz * Bz / 64, 256, 0, stream>>>(hcat, Wout_c, bout, out);

    crf_num<<<Bz, 256, 0, stream>>>(out, sent, tags, lengths, trans, start_t, end_t, num);
    crf_den<<<Bz, 64, 0, stream>>>(out, lengths, trans, start_t, end_t, den);
    crf_loss<<<1, 64, 0, stream>>>(num, den, loss_out);
}